// Round 2
// baseline (9.756 us; speedup 1.0000x reference)
//
#include <hip/hip_runtime.h>

#define BATCH 16384
#define SPLIT 16   // lanes per batch element

__global__ __launch_bounds__(256) void neumf_kernel(
    const int*   __restrict__ user_ids,
    const int*   __restrict__ movie_ids,
    const float* __restrict__ gmf_user,   // [NU, 64]
    const float* __restrict__ gmf_movie,  // [NM, 64]
    const float* __restrict__ mlp_user,   // [NU, 8]
    const float* __restrict__ mlp_movie,  // [NM, 8]
    const float* __restrict__ W1,         // [16, 8]
    const float* __restrict__ b1,         // [8]
    const float* __restrict__ W2,         // [8, 4]
    const float* __restrict__ b2,         // [4]
    const float* __restrict__ Wf,         // [68, 1]
    const float* __restrict__ bf,         // [1]
    float*       __restrict__ out)        // [BATCH]
{
    const int tid   = blockIdx.x * blockDim.x + threadIdx.x;
    const int elem  = tid >> 4;        // batch element
    const int lane  = tid & (SPLIT - 1);
    if (elem >= BATCH) return;

    const int uid = user_ids[elem];
    const int mid = movie_ids[elem];

    // ---- GMF: lanes 0..15 each take one float4 chunk of the 64-float row.
    // Consecutive lanes -> consecutive addresses -> coalesced.
    const float4 u = ((const float4*)(gmf_user  + (size_t)uid * 64))[lane];
    const float4 m = ((const float4*)(gmf_movie + (size_t)mid * 64))[lane];
    const float4 w = ((const float4*)Wf)[lane];   // Wf[lane*4 .. +3]

    float acc = u.x * m.x * w.x;
    acc = fmaf(u.y * m.y, w.y, acc);
    acc = fmaf(u.z * m.z, w.z, acc);
    acc = fmaf(u.w * m.w, w.w, acc);

    // reduce GMF partial dot across the 16-lane group
    acc += __shfl_xor(acc, 1);
    acc += __shfl_xor(acc, 2);
    acc += __shfl_xor(acc, 4);
    acc += __shfl_xor(acc, 8);

    // ---- MLP input: 4 float4 chunks; lane holds chunk (lane & 3).
    // chunk 0,1 = mlp_user[uid], chunk 2,3 = mlp_movie[mid]
    const float* mp = (lane & 2) ? (mlp_movie + (size_t)mid * 8)
                                 : (mlp_user  + (size_t)uid * 8);
    const float4 mlpv = ((const float4*)mp)[lane & 1];

    // broadcast all 16 inputs to every lane in the group
    float in16[16];
    #pragma unroll
    for (int c = 0; c < 4; ++c) {
        in16[c * 4 + 0] = __shfl(mlpv.x, c, SPLIT);
        in16[c * 4 + 1] = __shfl(mlpv.y, c, SPLIT);
        in16[c * 4 + 2] = __shfl(mlpv.z, c, SPLIT);
        in16[c * 4 + 3] = __shfl(mlpv.w, c, SPLIT);
    }

    // tiny MLP, computed redundantly on all lanes (VALU is idle)
    float h1[8];
    #pragma unroll
    for (int j = 0; j < 8; ++j) {
        float s = b1[j];
        #pragma unroll
        for (int k = 0; k < 16; ++k) s = fmaf(in16[k], W1[k * 8 + j], s);
        h1[j] = fmaxf(s, 0.f);
    }

    float mlp_acc = 0.f;
    #pragma unroll
    for (int j = 0; j < 4; ++j) {
        float s = b2[j];
        #pragma unroll
        for (int k = 0; k < 8; ++k) s = fmaf(h1[k], W2[k * 4 + j], s);
        s = fmaxf(s, 0.f);
        mlp_acc = fmaf(s, Wf[64 + j], mlp_acc);
    }

    if (lane == 0) {
        const float logit = acc + mlp_acc + bf[0];
        const float sig = 1.f / (1.f + __expf(-logit));
        out[elem] = sig * 4.f + 1.f;
    }
}

extern "C" void kernel_launch(void* const* d_in, const int* in_sizes, int n_in,
                              void* d_out, int out_size, void* d_ws, size_t ws_size,
                              hipStream_t stream) {
    const int*   user_ids  = (const int*)  d_in[0];
    const int*   movie_ids = (const int*)  d_in[1];
    const float* gmf_user  = (const float*)d_in[2];
    const float* gmf_movie = (const float*)d_in[3];
    const float* mlp_user  = (const float*)d_in[4];
    const float* mlp_movie = (const float*)d_in[5];
    const float* W1        = (const float*)d_in[6];
    const float* b1        = (const float*)d_in[7];
    const float* W2        = (const float*)d_in[8];
    const float* b2        = (const float*)d_in[9];
    const float* Wf        = (const float*)d_in[10];
    const float* bf        = (const float*)d_in[11];
    float*       out       = (float*)d_out;

    const int threads = 256;
    const int total   = BATCH * SPLIT;           // 262144 threads
    const int blocks  = (total + threads - 1) / threads;  // 1024 blocks
    neumf_kernel<<<blocks, threads, 0, stream>>>(
        user_ids, movie_ids, gmf_user, gmf_movie, mlp_user, mlp_movie,
        W1, b1, W2, b2, Wf, bf, out);
}